// Round 1
// baseline (378.804 us; speedup 1.0000x reference)
//
#include <hip/hip_runtime.h>
#include <math.h>

// Problem constants
#define Bsz 4
#define Lseq 2048
#define Dd 64
#define DIN 128
#define DST 64
#define DCONV 4
#define DTR 4
#define FFIN 256
#define FFK 4
#define NC 16      // scan chunks
#define CT 128     // chunk length (NC*CT == Lseq)
#define LP3 2051   // Lseq + 3 (ff intermediate length)

// ws layout (float offsets)
#define OFF_XZ    0u          // B*L*256 = 2,097,152
#define OFF_XC    2097152u    // B*L*128 = 1,048,576
#define OFF_DT    3145728u    // B*L*128
#define OFF_BM    4194304u    // B*L*64
#define OFF_CM    4718592u    // B*L*64
#define OFF_Y     5242880u    // B*L*128
#define OFF_H2    6291456u    // B*L*64
#define OFF_P     6815744u    // 32768*NC = 524,288
#define OFF_HLOC  7340032u
#define OFF_HINIT 7864320u
#define OFF_HH    OFF_DT      // aliases dt/Bm/Cm/y-head (dead by the time ff1 runs)
// total needed: 8,388,608 floats = 33.5 MB

__device__ __forceinline__ float silu_f(float x) {
    return x / (1.f + __expf(-x));
}
__device__ __forceinline__ float softplus_f(float x) {
    return x > 0.f ? x + log1pf(__expf(-x)) : log1pf(__expf(x));
}

// K1: xz[b,l,e] = sum_d x[b,l,d] * in_proj_w[e,d]   (rows=16 per block, 256 threads = e)
__global__ __launch_bounds__(256) void k_inproj(const float* __restrict__ x,
                                                const float* __restrict__ w,
                                                float* __restrict__ xz) {
    __shared__ __align__(16) float4 xs[16 * 16]; // 16 rows x 64 floats
    int tid = threadIdx.x;
    int row0 = blockIdx.x * 16;
    const float4* xg = (const float4*)(x + (size_t)row0 * 64);
    xs[tid] = xg[tid];
    __syncthreads();
    float4 wreg[16];
    const float4* wg = (const float4*)(w + (size_t)tid * 64);
#pragma unroll
    for (int i = 0; i < 16; i++) wreg[i] = wg[i];
    for (int r = 0; r < 16; r++) {
        float acc = 0.f;
#pragma unroll
        for (int i = 0; i < 16; i++) {
            float4 a = xs[r * 16 + i], b = wreg[i];
            acc += a.x * b.x + a.y * b.y + a.z * b.z + a.w * b.w;
        }
        xz[(size_t)(row0 + r) * 256 + tid] = acc;
    }
}

// K2: causal depthwise conv + silu -> xc[b,l,c]
__global__ __launch_bounds__(256) void k_conv(const float* __restrict__ xz,
                                              const float* __restrict__ cw,
                                              const float* __restrict__ cb,
                                              float* __restrict__ xc) {
    int idx = blockIdx.x * 256 + threadIdx.x; // B*L*128
    int c = idx & 127;
    int t = idx >> 7;
    int b = t >> 11;
    int l = t & 2047;
    float4 w = ((const float4*)cw)[c];
    float wk[4] = {w.x, w.y, w.z, w.w};
    float acc = cb[c];
#pragma unroll
    for (int k = 0; k < 4; k++) {
        int ll = l - 3 + k;
        if (ll >= 0) acc += xz[((size_t)(b * Lseq + ll)) * 256 + c] * wk[k];
    }
    xc[idx] = silu_f(acc);
}

// K3: xdb = xc @ x_proj_w^T (132 cols), then dt = softplus(dtr @ dt_proj_w^T + b)
__global__ __launch_bounds__(128) void k_xproj(const float* __restrict__ xc,
                                               const float* __restrict__ xpw,
                                               const float* __restrict__ dtw,
                                               const float* __restrict__ dtb,
                                               float* __restrict__ dt,
                                               float* __restrict__ Bm,
                                               float* __restrict__ Cm) {
    __shared__ __align__(16) float xcs[16 * 128];
    __shared__ float dtrs[16][4];
    int tid = threadIdx.x;
    int row0 = blockIdx.x * 16;
    const float4* src = (const float4*)(xc + (size_t)row0 * 128);
    float4* dst = (float4*)xcs;
#pragma unroll
    for (int i = 0; i < 4; i++) dst[tid + 128 * i] = src[tid + 128 * i];
    __syncthreads();
    const float4* wr = (const float4*)(xpw + (size_t)tid * 128);
    float4 w[32];
#pragma unroll
    for (int i = 0; i < 32; i++) w[i] = wr[i];
    const float4* wr2 = (const float4*)(xpw + (size_t)(128 + tid) * 128); // used when tid<4
    for (int r = 0; r < 16; r++) {
        const float4* a4 = (const float4*)(xcs + r * 128);
        float acc = 0.f;
#pragma unroll
        for (int i = 0; i < 32; i++) {
            float4 a = a4[i], b = w[i];
            acc += a.x * b.x + a.y * b.y + a.z * b.z + a.w * b.w;
        }
        int row = row0 + r;
        if (tid < 4) {
            dtrs[r][tid] = acc;
            float acc2 = 0.f;
#pragma unroll
            for (int i = 0; i < 32; i++) {
                float4 a = a4[i], b = wr2[i];
                acc2 += a.x * b.x + a.y * b.y + a.z * b.z + a.w * b.w;
            }
            Cm[(size_t)row * 64 + 60 + tid] = acc2; // cols 128..131 -> s=60..63
        } else if (tid < 68) {
            Bm[(size_t)row * 64 + (tid - 4)] = acc;
        } else {
            Cm[(size_t)row * 64 + (tid - 68)] = acc;
        }
    }
    __syncthreads();
    float4 w4 = ((const float4*)dtw)[tid];
    float bb = dtb[tid];
    for (int r = 0; r < 16; r++) {
        float xv = bb + dtrs[r][0] * w4.x + dtrs[r][1] * w4.y + dtrs[r][2] * w4.z + dtrs[r][3] * w4.w;
        dt[(size_t)(row0 + r) * 128 + tid] = softplus_f(xv);
    }
}

// K4: scan pass A — per (b,chunk,d,s): chunk decay product P and zero-init local state
__global__ __launch_bounds__(256) void k_scanA(const float* __restrict__ dt,
                                               const float* __restrict__ xc,
                                               const float* __restrict__ Bm,
                                               const float* __restrict__ Alog,
                                               float* __restrict__ P,
                                               float* __restrict__ hloc) {
    int tid = threadIdx.x;
    int s = tid & 63, wv = tid >> 6;
    int blk = blockIdx.x; // ((b*NC + chunk)*32 + dg)
    int dg = blk & 31;
    int t = blk >> 5;
    int chunk = t & 15;
    int b = t >> 4;
    int d = dg * 4 + wv;
    float A = -__expf(Alog[d * 64 + s]);
    float h = 0.f, Pp = 1.f;
    int base = b * Lseq + chunk * CT;
    for (int i = 0; i < CT; i++) {
        size_t off = (size_t)(base + i);
        float dtv = dt[off * 128 + d];
        float xcv = xc[off * 128 + d];
        float bmv = Bm[off * 64 + s];
        float a = __expf(dtv * A);
        h = fmaf(a, h, dtv * bmv * xcv);
        Pp *= a;
    }
    size_t idx = (((size_t)chunk * Bsz + b) * 128 + d) * 64 + s;
    P[idx] = Pp;
    hloc[idx] = h;
}

// K5: sequential combine over chunks
__global__ __launch_bounds__(256) void k_comb(const float* __restrict__ P,
                                              const float* __restrict__ hloc,
                                              float* __restrict__ Hinit) {
    int n = blockIdx.x * 256 + threadIdx.x; // 32768 = (b*128+d)*64+s
    float H = 0.f;
#pragma unroll
    for (int j = 0; j < NC; j++) {
        size_t idx = (size_t)j * 32768 + n;
        Hinit[idx] = H;
        H = hloc[idx] + P[idx] * H;
    }
}

// K6: scan pass B — replay with correct init, y[b,l,d] = sum_s h*C via wave reduction
__global__ __launch_bounds__(256) void k_scanB(const float* __restrict__ dt,
                                               const float* __restrict__ xc,
                                               const float* __restrict__ Bm,
                                               const float* __restrict__ Cm,
                                               const float* __restrict__ Alog,
                                               const float* __restrict__ Hinit,
                                               float* __restrict__ y) {
    int tid = threadIdx.x;
    int s = tid & 63, wv = tid >> 6;
    int blk = blockIdx.x;
    int dg = blk & 31;
    int t = blk >> 5;
    int chunk = t & 15;
    int b = t >> 4;
    int d = dg * 4 + wv;
    float A = -__expf(Alog[d * 64 + s]);
    float h = Hinit[(((size_t)chunk * Bsz + b) * 128 + d) * 64 + s];
    int base = b * Lseq + chunk * CT;
    for (int i = 0; i < CT; i++) {
        size_t off = (size_t)(base + i);
        float dtv = dt[off * 128 + d];
        float xcv = xc[off * 128 + d];
        float bmv = Bm[off * 64 + s];
        float cmv = Cm[off * 64 + s];
        float a = __expf(dtv * A);
        h = fmaf(a, h, dtv * bmv * xcv);
        float p = h * cmv;
        p += __shfl_xor(p, 1);
        p += __shfl_xor(p, 2);
        p += __shfl_xor(p, 4);
        p += __shfl_xor(p, 8);
        p += __shfl_xor(p, 16);
        p += __shfl_xor(p, 32);
        if (s == 0) y[off * 128 + d] = p;
    }
}

// K7: y gate + out_proj + leaky_relu + rms-groupnorm -> h2
__global__ __launch_bounds__(256) void k_gate(const float* __restrict__ y,
                                              const float* __restrict__ xc,
                                              const float* __restrict__ xz,
                                              const float* __restrict__ Dp,
                                              const float* __restrict__ opw,
                                              const float* __restrict__ gamma,
                                              float* __restrict__ h2) {
    __shared__ __align__(16) float ys[16 * 128];
    __shared__ float hs[16 * 64];
    int tid = threadIdx.x;
    int row0 = blockIdx.x * 16;
#pragma unroll
    for (int i = 0; i < 8; i++) {
        int idx = tid + 256 * i;
        int r = idx >> 7, dd = idx & 127;
        size_t off = (size_t)(row0 + r);
        float yv = y[off * 128 + dd];
        float xcv = xc[off * 128 + dd];
        float zv = xz[off * 256 + 128 + dd];
        ys[idx] = (yv + xcv * Dp[dd]) * silu_f(zv);
    }
    __syncthreads();
    int e = tid & 63, rr = tid >> 6;
    const float4* wr = (const float4*)(opw + (size_t)e * 128);
    float4 w[32];
#pragma unroll
    for (int i = 0; i < 32; i++) w[i] = wr[i];
#pragma unroll
    for (int j = 0; j < 4; j++) {
        int r = rr + 4 * j;
        const float4* a4 = (const float4*)(ys + r * 128);
        float acc = 0.f;
#pragma unroll
        for (int i = 0; i < 32; i++) {
            float4 a = a4[i], b = w[i];
            acc += a.x * b.x + a.y * b.y + a.z * b.z + a.w * b.w;
        }
        acc = acc >= 0.f ? acc : 0.01f * acc;
        hs[r * 64 + e] = acc;
    }
    __syncthreads();
#pragma unroll
    for (int j = 0; j < 4; j++) {
        int r = rr + 4 * j;
        int g = e >> 4;
        float ss = 0.f;
#pragma unroll
        for (int i = 0; i < 16; i++) {
            float v = hs[r * 64 + g * 16 + i];
            ss += v * v;
        }
        float rms = sqrtf(ss) * 0.25f;
        h2[(size_t)(row0 + r) * 64 + e] = hs[r * 64 + e] / (rms + 1e-5f) * gamma[e];
    }
}

// K8: FF conv1 (K=4, pad +-3 overall) + GLU -> hh[b][t][c], t in [0, L+3)
__global__ __launch_bounds__(256) void k_ff1(const float* __restrict__ h2,
                                             const float* __restrict__ fw,
                                             const float* __restrict__ fb,
                                             float* __restrict__ hh) {
    __shared__ __align__(16) float xs[19 * 64];
    int tid = threadIdx.x;
    int blk = blockIdx.x; // b*129 + tb
    int tb = blk % 129, b = blk / 129;
    int t0 = tb * 16;
    for (int i = tid; i < 19 * 64; i += 256) {
        int m = i >> 6, dd = i & 63;
        int tr = t0 + m - 3;
        xs[i] = (tr >= 0 && tr < Lseq) ? h2[(size_t)(b * Lseq + tr) * 64 + dd] : 0.f;
    }
    __syncthreads();
    int c = tid;
    float bu = fb[c], bg = fb[c + 256];
    float accu[16], accg[16];
#pragma unroll
    for (int r = 0; r < 16; r++) { accu[r] = bu; accg[r] = bg; }
    const float4* wu4 = (const float4*)(fw + (size_t)c * 256);
    const float4* wg4 = (const float4*)(fw + (size_t)(c + 256) * 256);
    for (int d = 0; d < 64; d++) {
        float4 wu = wu4[d], wg = wg4[d];
        float xv[19];
#pragma unroll
        for (int m = 0; m < 19; m++) xv[m] = xs[m * 64 + d];
#pragma unroll
        for (int r = 0; r < 16; r++) {
            accu[r] += xv[r] * wu.x + xv[r + 1] * wu.y + xv[r + 2] * wu.z + xv[r + 3] * wu.w;
            accg[r] += xv[r] * wg.x + xv[r + 1] * wg.y + xv[r + 2] * wg.z + xv[r + 3] * wg.w;
        }
    }
    for (int r = 0; r < 16; r++) {
        int t = t0 + r;
        if (t < LP3) {
            float g = accg[r];
            hh[(size_t)(b * LP3 + t) * 256 + c] = accu[r] * silu_f(g);
        }
    }
}

// K9: FF conv2 (transposed, kernel flipped) + residual: out = h2 + 0.5*(deconv + db)
__global__ __launch_bounds__(256) void k_ff2(const float* __restrict__ hh,
                                             const float* __restrict__ h2,
                                             const float* __restrict__ dw,
                                             const float* __restrict__ db,
                                             float* __restrict__ out) {
    __shared__ __align__(16) float hsm[256 * 20]; // [c][t], stride 20 (16B-aligned rows)
    int tid = threadIdx.x;
    int blk = blockIdx.x; // b*128 + lb
    int lb = blk & 127, b = blk >> 7;
    int l0 = lb * 16;
    for (int i = tid; i < 19 * 256; i += 256) {
        int j = i >> 8, c = i & 255;
        hsm[c * 20 + j] = hh[(size_t)(b * LP3 + l0 + j) * 256 + c];
    }
    __syncthreads();
    int e = tid & 63, wv = tid >> 6; // wave wv handles rows wv*4 .. wv*4+3
    float acc[4] = {0.f, 0.f, 0.f, 0.f};
    for (int c = 0; c < 256; c++) {
        float4 d4 = *(const float4*)(dw + ((size_t)c * 64 + e) * 4);
        const float4* hp = (const float4*)(hsm + c * 20 + wv * 4);
        float4 h0 = hp[0], h1 = hp[1];
        float hv[8] = {h0.x, h0.y, h0.z, h0.w, h1.x, h1.y, h1.z, h1.w};
#pragma unroll
        for (int r = 0; r < 4; r++) {
            acc[r] += hv[r] * d4.w + hv[r + 1] * d4.z + hv[r + 2] * d4.y + hv[r + 3] * d4.x;
        }
    }
#pragma unroll
    for (int r = 0; r < 4; r++) {
        int l = l0 + wv * 4 + r;
        size_t off = (size_t)(b * Lseq + l) * 64 + e;
        out[off] = h2[off] + 0.5f * (acc[r] + db[e]);
    }
}

extern "C" void kernel_launch(void* const* d_in, const int* in_sizes, int n_in,
                              void* d_out, int out_size, void* d_ws, size_t ws_size,
                              hipStream_t stream) {
    const float* x      = (const float*)d_in[0];
    const float* ipw    = (const float*)d_in[1];
    const float* cw     = (const float*)d_in[2];
    const float* cb     = (const float*)d_in[3];
    const float* xpw    = (const float*)d_in[4];
    const float* dtw    = (const float*)d_in[5];
    const float* dtb    = (const float*)d_in[6];
    const float* Alog   = (const float*)d_in[7];
    const float* Dp     = (const float*)d_in[8];
    const float* opw    = (const float*)d_in[9];
    const float* gamma  = (const float*)d_in[10];
    const float* fcw    = (const float*)d_in[11];
    const float* fcb    = (const float*)d_in[12];
    const float* fdw    = (const float*)d_in[13];
    const float* fdb    = (const float*)d_in[14];
    float* out = (float*)d_out;
    float* ws = (float*)d_ws;

    float* xz    = ws + OFF_XZ;
    float* xc    = ws + OFF_XC;
    float* dt    = ws + OFF_DT;
    float* Bm    = ws + OFF_BM;
    float* Cm    = ws + OFF_CM;
    float* y     = ws + OFF_Y;
    float* h2    = ws + OFF_H2;
    float* P     = ws + OFF_P;
    float* hloc  = ws + OFF_HLOC;
    float* Hinit = ws + OFF_HINIT;
    float* hh    = ws + OFF_HH;

    hipLaunchKernelGGL(k_inproj, dim3(512), dim3(256), 0, stream, x, ipw, xz);
    hipLaunchKernelGGL(k_conv, dim3(4096), dim3(256), 0, stream, xz, cw, cb, xc);
    hipLaunchKernelGGL(k_xproj, dim3(512), dim3(128), 0, stream, xc, xpw, dtw, dtb, dt, Bm, Cm);
    hipLaunchKernelGGL(k_scanA, dim3(2048), dim3(256), 0, stream, dt, xc, Bm, Alog, P, hloc);
    hipLaunchKernelGGL(k_comb, dim3(128), dim3(256), 0, stream, P, hloc, Hinit);
    hipLaunchKernelGGL(k_scanB, dim3(2048), dim3(256), 0, stream, dt, xc, Bm, Cm, Alog, Hinit, y);
    hipLaunchKernelGGL(k_gate, dim3(512), dim3(256), 0, stream, y, xc, xz, Dp, opw, gamma, h2);
    hipLaunchKernelGGL(k_ff1, dim3(516), dim3(256), 0, stream, h2, fcw, fcb, hh);
    hipLaunchKernelGGL(k_ff2, dim3(512), dim3(256), 0, stream, hh, h2, fdw, fdb, out);
}

// Round 2
// 373.531 us; speedup vs baseline: 1.0141x; 1.0141x over previous
//
#include <hip/hip_runtime.h>
#include <math.h>

// Problem constants
#define Bsz 4
#define Lseq 2048
#define DIN 128
#define DST 64
#define FFIN 256
#define NC 32      // scan chunks
#define CT 64      // chunk length (NC*CT == Lseq)
#define LP3 2051   // Lseq + 3 (ff intermediate length)
#define FT 17      // ff1 t-tile

// ws layout (float offsets) — total 7,864,320 floats = 30 MiB (< proven 32 MiB)
#define OFF_Z     0u          // B*L*128 = 1,048,576
#define OFF_XC    1048576u
#define OFF_DT    2097152u
#define OFF_BM    3145728u    // B*L*64
#define OFF_CM    3670016u
#define OFF_Y     4194304u    // B*L*128
#define OFF_H2    5242880u    // B*L*64
#define OFF_XIN   5767168u    // dead after k_conv -> reused as hloc
#define OFF_P     6815744u    // NC*32768 = 1,048,576 ; becomes Hinit after k_comb
#define OFF_HH    OFF_DT      // 2,100,224 floats; overlays dt/Bm/Cm/y-head (dead after gate)

__device__ __forceinline__ float silu_f(float x) {
    return x / (1.f + __expf(-x));
}
__device__ __forceinline__ float softplus_f(float x) {
    return x > 0.f ? x + log1pf(__expf(-x)) : log1pf(__expf(x));
}

// K1: xz = x @ in_proj_w^T ; split into xin (cols 0..127) and z (cols 128..255)
// lanes = output col (uniform x row -> scalar loads), weights one-time to regs.
__global__ __launch_bounds__(256) void k_inproj(const float* __restrict__ x,
                                                const float* __restrict__ w,
                                                float* __restrict__ xin,
                                                float* __restrict__ z) {
    int tid = threadIdx.x;
    int row0 = blockIdx.x * 16;
    float wreg[64];
    {
        const float4* wg = (const float4*)(w + (size_t)tid * 64);
#pragma unroll
        for (int i = 0; i < 16; i++) {
            float4 v = wg[i];
            wreg[i*4+0]=v.x; wreg[i*4+1]=v.y; wreg[i*4+2]=v.z; wreg[i*4+3]=v.w;
        }
    }
    for (int r = 0; r < 16; r++) {
        const float* xr = x + (size_t)(row0 + r) * 64;   // uniform address
        float a0=0.f,a1=0.f,a2=0.f,a3=0.f;
#pragma unroll
        for (int i = 0; i < 64; i += 4) {
            a0 = fmaf(xr[i+0], wreg[i+0], a0);
            a1 = fmaf(xr[i+1], wreg[i+1], a1);
            a2 = fmaf(xr[i+2], wreg[i+2], a2);
            a3 = fmaf(xr[i+3], wreg[i+3], a3);
        }
        float acc = (a0+a1)+(a2+a3);
        if (tid < 128) xin[(size_t)(row0+r)*128 + tid] = acc;
        else           z[(size_t)(row0+r)*128 + (tid-128)] = acc;
    }
}

// K2: causal depthwise conv + silu -> xc
__global__ __launch_bounds__(256) void k_conv(const float* __restrict__ xin,
                                              const float* __restrict__ cw,
                                              const float* __restrict__ cb,
                                              float* __restrict__ xc) {
    int idx = blockIdx.x * 256 + threadIdx.x; // B*L*128
    int c = idx & 127;
    int t = idx >> 7;
    int b = t >> 11;
    int l = t & 2047;
    float4 w = ((const float4*)cw)[c];
    float wk[4] = {w.x, w.y, w.z, w.w};
    float acc = cb[c];
#pragma unroll
    for (int k = 0; k < 4; k++) {
        int ll = l - 3 + k;
        if (ll >= 0) acc += xin[((size_t)(b * Lseq + ll)) * 128 + c] * wk[k];
    }
    xc[idx] = silu_f(acc);
}

// K3: xdb = xc @ x_proj_w^T (132 cols) + dt = softplus(dtr @ dt_proj_w^T + b)
// lanes = col; xc row uniform -> scalar loads; w rows one-time to regs.
__global__ __launch_bounds__(128) void k_xproj(const float* __restrict__ xc,
                                               const float* __restrict__ xpw,
                                               const float* __restrict__ dtw,
                                               const float* __restrict__ dtb,
                                               float* __restrict__ dt,
                                               float* __restrict__ Bm,
                                               float* __restrict__ Cm) {
    __shared__ float dtrs[16][4];
    int tid = threadIdx.x;
    int row0 = blockIdx.x * 16;
    float wreg[128];
    {
        const float4* wg = (const float4*)(xpw + (size_t)tid * 128);
#pragma unroll
        for (int i = 0; i < 32; i++) {
            float4 v = wg[i];
            wreg[i*4+0]=v.x; wreg[i*4+1]=v.y; wreg[i*4+2]=v.z; wreg[i*4+3]=v.w;
        }
    }
    int c2 = 128 + (tid >> 5);        // extra cols 128..131
    int j0 = (tid & 31) * 4;
    float4 we = *(const float4*)(xpw + (size_t)c2 * 128 + j0);  // coalesced
    for (int r = 0; r < 16; r++) {
        const float* xr = xc + (size_t)(row0 + r) * 128;   // uniform
        float a0=0.f,a1=0.f,a2=0.f,a3=0.f;
#pragma unroll
        for (int i = 0; i < 128; i += 4) {
            a0 = fmaf(xr[i+0], wreg[i+0], a0);
            a1 = fmaf(xr[i+1], wreg[i+1], a1);
            a2 = fmaf(xr[i+2], wreg[i+2], a2);
            a3 = fmaf(xr[i+3], wreg[i+3], a3);
        }
        float acc = (a0+a1)+(a2+a3);
        int row = row0 + r;
        if (tid < 4) dtrs[r][tid] = acc;
        else if (tid < 68) Bm[(size_t)row*64 + (tid-4)] = acc;
        else Cm[(size_t)row*64 + (tid-68)] = acc;
        // extra cols: per-lane partial + 32-lane reduce
        float4 xr4 = ((const float4*)xr)[tid & 31];
        float p = xr4.x*we.x + xr4.y*we.y + xr4.z*we.z + xr4.w*we.w;
        p += __shfl_xor(p, 1); p += __shfl_xor(p, 2); p += __shfl_xor(p, 4);
        p += __shfl_xor(p, 8); p += __shfl_xor(p, 16);
        if ((tid & 31) == 0) Cm[(size_t)row*64 + 60 + (tid>>5)] = p;
    }
    __syncthreads();
    float4 w4 = ((const float4*)dtw)[tid];
    float bb = dtb[tid];
    for (int r = 0; r < 16; r++) {
        float xv = bb + dtrs[r][0]*w4.x + dtrs[r][1]*w4.y + dtrs[r][2]*w4.z + dtrs[r][3]*w4.w;
        dt[(size_t)(row0+r)*128 + tid] = softplus_f(xv);
    }
}

// K4: scan pass A — lane holds 8 s-states; per (b,chunk,d): decay product + local state
__global__ __launch_bounds__(256) void k_scanA(const float* __restrict__ dt,
                                               const float* __restrict__ xc,
                                               const float* __restrict__ Bm,
                                               const float* __restrict__ Alog,
                                               float* __restrict__ P,
                                               float* __restrict__ hloc) {
    int tid = threadIdx.x;
    int lane = tid & 63, wv = tid >> 6;
    int blk = blockIdx.x;           // ((b*32 + nc)*4 + dgq)
    int dgq = blk & 3;
    int t = blk >> 2;
    int nc = t & 31;
    int b = t >> 5;
    int dgroup = dgq * 4 + wv;      // 0..15
    int dd = lane >> 3, sg = lane & 7;
    int d = dgroup * 8 + dd;
    float A[8], h[8], Pp[8];
#pragma unroll
    for (int j = 0; j < 8; j++) {
        A[j] = -__expf(Alog[d*64 + sg*8 + j]);
        h[j] = 0.f; Pp[j] = 1.f;
    }
    int base = b * Lseq + nc * CT;
    for (int i = 0; i < CT; i++) {
        size_t off = (size_t)(base + i);
        float dtv = dt[off*128 + d];
        float xcv = xc[off*128 + d];
        const float4* bm4 = (const float4*)(Bm + off*64 + sg*8);
        float4 b0 = bm4[0], b1 = bm4[1];
        float bmv[8] = {b0.x,b0.y,b0.z,b0.w,b1.x,b1.y,b1.z,b1.w};
        float dtxc = dtv * xcv;
#pragma unroll
        for (int j = 0; j < 8; j++) {
            float a = __expf(dtv * A[j]);
            h[j] = fmaf(a, h[j], dtxc * bmv[j]);
            Pp[j] *= a;
        }
    }
    size_t idx0 = (((size_t)nc*4 + b)*128 + d)*64 + sg*8;
    float4* p4 = (float4*)(P + idx0);
    p4[0] = make_float4(Pp[0],Pp[1],Pp[2],Pp[3]);
    p4[1] = make_float4(Pp[4],Pp[5],Pp[6],Pp[7]);
    float4* h4 = (float4*)(hloc + idx0);
    h4[0] = make_float4(h[0],h[1],h[2],h[3]);
    h4[1] = make_float4(h[4],h[5],h[6],h[7]);
}

// K5: sequential combine over chunks; writes Hinit in-place into P
__global__ __launch_bounds__(256) void k_comb(float* __restrict__ P,
                                              const float* __restrict__ hloc) {
    int n = blockIdx.x * 256 + threadIdx.x; // 32768 = (b*128+d)*64+s
    float pv[NC], hv[NC];
#pragma unroll
    for (int j = 0; j < NC; j++) {
        size_t idx = (size_t)j * 32768 + n;
        pv[j] = P[idx];
        hv[j] = hloc[idx];
    }
    float H = 0.f;
#pragma unroll
    for (int j = 0; j < NC; j++) {
        P[(size_t)j * 32768 + n] = H;
        H = fmaf(pv[j], H, hv[j]);
    }
}

// K6: scan pass B — replay with Hinit, y = sum_s h*C via 3 shuffles (8 lanes per d)
__global__ __launch_bounds__(256) void k_scanB(const float* __restrict__ dt,
                                               const float* __restrict__ xc,
                                               const float* __restrict__ Bm,
                                               const float* __restrict__ Cm,
                                               const float* __restrict__ Alog,
                                               const float* __restrict__ Hinit,
                                               float* __restrict__ y) {
    int tid = threadIdx.x;
    int lane = tid & 63, wv = tid >> 6;
    int blk = blockIdx.x;
    int dgq = blk & 3;
    int t = blk >> 2;
    int nc = t & 31;
    int b = t >> 5;
    int dgroup = dgq * 4 + wv;
    int dd = lane >> 3, sg = lane & 7;
    int d = dgroup * 8 + dd;
    float A[8], h[8];
    size_t idx0 = (((size_t)nc*4 + b)*128 + d)*64 + sg*8;
    {
        const float4* h4 = (const float4*)(Hinit + idx0);
        float4 h0 = h4[0], h1 = h4[1];
        h[0]=h0.x; h[1]=h0.y; h[2]=h0.z; h[3]=h0.w;
        h[4]=h1.x; h[5]=h1.y; h[6]=h1.z; h[7]=h1.w;
    }
#pragma unroll
    for (int j = 0; j < 8; j++) A[j] = -__expf(Alog[d*64 + sg*8 + j]);
    int base = b * Lseq + nc * CT;
    for (int i = 0; i < CT; i++) {
        size_t off = (size_t)(base + i);
        float dtv = dt[off*128 + d];
        float xcv = xc[off*128 + d];
        const float4* bm4 = (const float4*)(Bm + off*64 + sg*8);
        float4 b0 = bm4[0], b1 = bm4[1];
        const float4* cm4 = (const float4*)(Cm + off*64 + sg*8);
        float4 c0 = cm4[0], c1 = cm4[1];
        float bmv[8] = {b0.x,b0.y,b0.z,b0.w,b1.x,b1.y,b1.z,b1.w};
        float cmv[8] = {c0.x,c0.y,c0.z,c0.w,c1.x,c1.y,c1.z,c1.w};
        float dtxc = dtv * xcv;
        float p = 0.f;
#pragma unroll
        for (int j = 0; j < 8; j++) {
            float a = __expf(dtv * A[j]);
            h[j] = fmaf(a, h[j], dtxc * bmv[j]);
            p = fmaf(h[j], cmv[j], p);
        }
        p += __shfl_xor(p, 1);
        p += __shfl_xor(p, 2);
        p += __shfl_xor(p, 4);
        if (sg == 0) y[off*128 + d] = p;
    }
}

// K7: gate + out_proj + leaky_relu + rms-groupnorm -> h2
__global__ __launch_bounds__(256) void k_gate(const float* __restrict__ y,
                                              const float* __restrict__ xc,
                                              const float* __restrict__ z,
                                              const float* __restrict__ Dp,
                                              const float* __restrict__ opw,
                                              const float* __restrict__ gamma,
                                              float* __restrict__ h2) {
    __shared__ __align__(16) float ys[16 * 128];
    __shared__ float hs[16 * 64];
    int tid = threadIdx.x;
    int row0 = blockIdx.x * 16;
#pragma unroll
    for (int i = 0; i < 8; i++) {
        int idx = tid + 256 * i;
        int r = idx >> 7, dd = idx & 127;
        size_t off = (size_t)(row0 + r);
        float yv = y[off * 128 + dd];
        float xcv = xc[off * 128 + dd];
        float zv = z[off * 128 + dd];
        ys[idx] = (yv + xcv * Dp[dd]) * silu_f(zv);
    }
    __syncthreads();
    int e = tid & 63, rr = tid >> 6;
    const float4* wr = (const float4*)(opw + (size_t)e * 128);
    float4 w[32];
#pragma unroll
    for (int i = 0; i < 32; i++) w[i] = wr[i];
#pragma unroll
    for (int j = 0; j < 4; j++) {
        int r = rr + 4 * j;
        const float4* a4 = (const float4*)(ys + r * 128);
        float acc = 0.f;
#pragma unroll
        for (int i = 0; i < 32; i++) {
            float4 a = a4[i], b = w[i];
            acc += a.x * b.x + a.y * b.y + a.z * b.z + a.w * b.w;
        }
        acc = acc >= 0.f ? acc : 0.01f * acc;
        hs[r * 64 + e] = acc;
    }
    __syncthreads();
#pragma unroll
    for (int j = 0; j < 4; j++) {
        int r = rr + 4 * j;
        int g = e >> 4;
        float ss = 0.f;
#pragma unroll
        for (int i = 0; i < 16; i++) {
            float v = hs[r * 64 + g * 16 + i];
            ss += v * v;
        }
        float rms = sqrtf(ss) * 0.25f;
        h2[(size_t)(row0 + r) * 64 + e] = hs[r * 64 + e] / (rms + 1e-5f) * gamma[e];
    }
}

// K8: FF conv1 + GLU. Thread = channel pair (u=c, g=c+256). Weights chunked
// through LDS (conflict-free pad-17 rows); x window via uniform (scalar) loads.
__global__ __launch_bounds__(512) void k_ff1(const float* __restrict__ h2,
                                             const float* __restrict__ fw,
                                             const float* __restrict__ fb,
                                             float* __restrict__ hh) {
    __shared__ float wl[512 * 17];    // 34.8 KB
    int tid = threadIdx.x;            // 512
    int blk = blockIdx.x;             // b*121 + tb
    int tb = blk % 121, b = blk / 121;
    int t0 = tb * FT;
    int c = tid & 255;
    int isg = tid >> 8;               // 0 = u-half thread, 1 = g-half thread
    float accu[FT], accg[FT];
    {
        float bu = fb[c], bg = fb[c + 256];
#pragma unroll
        for (int r = 0; r < FT; r++) { accu[r] = bu; accg[r] = bg; }
    }
    const float4* fw4 = (const float4*)fw;
    for (int c4 = 0; c4 < 16; c4++) {   // chunks of 4 d (16 floats per row)
        __syncthreads();
        // stage fw[all 512 rows][c4*16 .. +16) -> wl[row][16] (pad 17)
#pragma unroll
        for (int swp = 0; swp < 4; swp++) {
            int g = swp * 512 + tid;      // 2048 float4
            int row = g >> 2, j4 = g & 3;
            float4 v = fw4[(size_t)row * 64 + c4 * 4 + j4];
            int bse = row * 17 + j4 * 4;
            wl[bse+0]=v.x; wl[bse+1]=v.y; wl[bse+2]=v.z; wl[bse+3]=v.w;
        }
        __syncthreads();
#pragma unroll
        for (int ddl = 0; ddl < 4; ddl++) {
            int d = c4 * 4 + ddl;
            float wu0 = wl[c*17 + ddl*4 + 0], wu1 = wl[c*17 + ddl*4 + 1];
            float wu2 = wl[c*17 + ddl*4 + 2], wu3 = wl[c*17 + ddl*4 + 3];
            float wg0 = wl[(c+256)*17 + ddl*4 + 0], wg1 = wl[(c+256)*17 + ddl*4 + 1];
            float wg2 = wl[(c+256)*17 + ddl*4 + 2], wg3 = wl[(c+256)*17 + ddl*4 + 3];
            float xw[FT + 3];
#pragma unroll
            for (int m = 0; m < FT + 3; m++) {
                int tt = t0 + m - 3;
                xw[m] = (tt >= 0 && tt < Lseq) ? h2[((size_t)(b*Lseq + tt))*64 + d] : 0.f;
            }
#pragma unroll
            for (int r = 0; r < FT; r++) {
                accu[r] += xw[r]*wu0 + xw[r+1]*wu1 + xw[r+2]*wu2 + xw[r+3]*wu3;
                accg[r] += xw[r]*wg0 + xw[r+1]*wg1 + xw[r+2]*wg2 + xw[r+3]*wg3;
            }
        }
    }
    // halve redundancy: low half writes even tiles' outputs... simply: both halves
    // computed the same accu/accg (tid and tid+256 pairs duplicate work on c);
    // let only the low 256 threads store.
    if (isg == 0) {
        for (int r = 0; r < FT; r++) {
            int t = t0 + r;
            if (t < LP3) hh[((size_t)(b*LP3 + t))*256 + c] = accu[r] * silu_f(accg[r]);
        }
    }
}

// K9: FF deconv + residual. lanes = e (dw coalesced 16B/lane); hh rows uniform
// per wave (readfirstlane) -> scalar loads. out = h2 + 0.5*(deconv + db)
__global__ __launch_bounds__(256) void k_ff2(const float* __restrict__ hh,
                                             const float* __restrict__ h2,
                                             const float* __restrict__ dw,
                                             const float* __restrict__ db,
                                             float* __restrict__ out) {
    int tid = threadIdx.x;
    int e = tid & 63;
    int tg = tid >> 6;              // wave id 0..3
    int blk = blockIdx.x;           // b*128 + lb
    int lb = blk & 127, b = blk >> 7;
    int t0u = __builtin_amdgcn_readfirstlane(lb * 16 + tg * 4);
    float acc0=0.f, acc1=0.f, acc2=0.f, acc3=0.f;
    const float4* dw4 = (const float4*)dw;
    const float* hbase = hh + (size_t)(b * LP3 + t0u) * 256;
    for (int cc = 0; cc < 256; cc++) {
        float4 w = dw4[(size_t)cc * 64 + e];
        const float* hp = hbase + cc;     // uniform
        float x0 = hp[0],    x1 = hp[256],  x2 = hp[512],  x3 = hp[768];
        float x4 = hp[1024], x5 = hp[1280], x6 = hp[1536];
        acc0 += x0*w.w + x1*w.z + x2*w.y + x3*w.x;
        acc1 += x1*w.w + x2*w.z + x3*w.y + x4*w.x;
        acc2 += x2*w.w + x3*w.z + x4*w.y + x5*w.x;
        acc3 += x3*w.w + x4*w.z + x5*w.y + x6*w.x;
    }
    float dbe = db[e];
    size_t ob = (size_t)(b * Lseq + t0u) * 64 + e;
    out[ob +   0] = h2[ob +   0] + 0.5f * (acc0 + dbe);
    out[ob +  64] = h2[ob +  64] + 0.5f * (acc1 + dbe);
    out[ob + 128] = h2[ob + 128] + 0.5f * (acc2 + dbe);
    out[ob + 192] = h2[ob + 192] + 0.5f * (acc3 + dbe);
}

extern "C" void kernel_launch(void* const* d_in, const int* in_sizes, int n_in,
                              void* d_out, int out_size, void* d_ws, size_t ws_size,
                              hipStream_t stream) {
    const float* x      = (const float*)d_in[0];
    const float* ipw    = (const float*)d_in[1];
    const float* cw     = (const float*)d_in[2];
    const float* cb     = (const float*)d_in[3];
    const float* xpw    = (const float*)d_in[4];
    const float* dtw    = (const float*)d_in[5];
    const float* dtb    = (const float*)d_in[6];
    const float* Alog   = (const float*)d_in[7];
    const float* Dp     = (const float*)d_in[8];
    const float* opw    = (const float*)d_in[9];
    const float* gamma  = (const float*)d_in[10];
    const float* fcw    = (const float*)d_in[11];
    const float* fcb    = (const float*)d_in[12];
    const float* fdw    = (const float*)d_in[13];
    const float* fdb    = (const float*)d_in[14];
    float* out = (float*)d_out;
    float* ws = (float*)d_ws;

    float* z     = ws + OFF_Z;
    float* xc    = ws + OFF_XC;
    float* dt    = ws + OFF_DT;
    float* Bm    = ws + OFF_BM;
    float* Cm    = ws + OFF_CM;
    float* y     = ws + OFF_Y;
    float* h2    = ws + OFF_H2;
    float* xin   = ws + OFF_XIN;   // becomes hloc after k_conv
    float* P     = ws + OFF_P;     // becomes Hinit after k_comb
    float* hh    = ws + OFF_HH;

    hipLaunchKernelGGL(k_inproj, dim3(512), dim3(256), 0, stream, x, ipw, xin, z);
    hipLaunchKernelGGL(k_conv,   dim3(4096), dim3(256), 0, stream, xin, cw, cb, xc);
    hipLaunchKernelGGL(k_xproj,  dim3(512), dim3(128), 0, stream, xc, xpw, dtw, dtb, dt, Bm, Cm);
    hipLaunchKernelGGL(k_scanA,  dim3(512), dim3(256), 0, stream, dt, xc, Bm, Alog, P, xin);
    hipLaunchKernelGGL(k_comb,   dim3(128), dim3(256), 0, stream, P, xin);
    hipLaunchKernelGGL(k_scanB,  dim3(512), dim3(256), 0, stream, dt, xc, Bm, Cm, Alog, P, y);
    hipLaunchKernelGGL(k_gate,   dim3(512), dim3(256), 0, stream, y, xc, z, Dp, opw, gamma, h2);
    hipLaunchKernelGGL(k_ff1,    dim3(484), dim3(512), 0, stream, h2, fcw, fcb, hh);
    hipLaunchKernelGGL(k_ff2,    dim3(512), dim3(256), 0, stream, hh, h2, fdw, fdb, out);
}

// Round 4
// 254.543 us; speedup vs baseline: 1.4882x; 1.4675x over previous
//
#include <hip/hip_runtime.h>
#include <math.h>

// Problem constants
#define Bsz 4
#define Lseq 2048
#define DIN 128
#define DST 64
#define FFIN 256
#define NC 32      // scan chunks
#define CT 64      // chunk length (NC*CT == Lseq)
#define LP3 2051   // Lseq + 3 (ff intermediate length)

// ws layout (float offsets)
#define OFF_Z     0u          // B*L*128 = 1,048,576
#define OFF_XC    1048576u
#define OFF_DT    2097152u
#define OFF_BM    3145728u    // B*L*64
#define OFF_CM    3670016u
#define OFF_Y     4194304u    // B*L*128
#define OFF_H2    5242880u    // B*L*64
#define OFF_XIN   5767168u    // dead after k_conv -> reused as hloc
#define OFF_P     6815744u    // scan P/Hinit; dead after scanB -> Wbf/dwt (bf16)
#define OFF_HH    OFF_DT      // hh bf16 (2,100,224 elems = 1,050,112 slots; spills
                              // 1536 slots into Bm region — Bm dead after scanB)

typedef __attribute__((ext_vector_type(8))) short bf16x8;
typedef __attribute__((ext_vector_type(4))) float f32x4;

__device__ __forceinline__ float silu_f(float x) {
    return x / (1.f + __expf(-x));
}
__device__ __forceinline__ float softplus_f(float x) {
    return x > 0.f ? x + log1pf(__expf(-x)) : log1pf(__expf(x));
}
__device__ __forceinline__ unsigned short f2bf(float f) {
    union { float f; unsigned u; } v; v.f = f;
    unsigned r = v.u + 0x7FFFu + ((v.u >> 16) & 1u);
    return (unsigned short)(r >> 16);
}

// K1: xz = x @ in_proj_w^T ; split into xin and z
__global__ __launch_bounds__(256) void k_inproj(const float* __restrict__ x,
                                                const float* __restrict__ w,
                                                float* __restrict__ xin,
                                                float* __restrict__ z) {
    int tid = threadIdx.x;
    int row0 = blockIdx.x * 16;
    float wreg[64];
    {
        const float4* wg = (const float4*)(w + (size_t)tid * 64);
#pragma unroll
        for (int i = 0; i < 16; i++) {
            float4 v = wg[i];
            wreg[i*4+0]=v.x; wreg[i*4+1]=v.y; wreg[i*4+2]=v.z; wreg[i*4+3]=v.w;
        }
    }
    for (int r = 0; r < 16; r++) {
        const float* xr = x + (size_t)(row0 + r) * 64;   // uniform address
        float a0=0.f,a1=0.f,a2=0.f,a3=0.f;
#pragma unroll
        for (int i = 0; i < 64; i += 4) {
            a0 = fmaf(xr[i+0], wreg[i+0], a0);
            a1 = fmaf(xr[i+1], wreg[i+1], a1);
            a2 = fmaf(xr[i+2], wreg[i+2], a2);
            a3 = fmaf(xr[i+3], wreg[i+3], a3);
        }
        float acc = (a0+a1)+(a2+a3);
        if (tid < 128) xin[(size_t)(row0+r)*128 + tid] = acc;
        else           z[(size_t)(row0+r)*128 + (tid-128)] = acc;
    }
}

// K2: causal depthwise conv + silu -> xc
__global__ __launch_bounds__(256) void k_conv(const float* __restrict__ xin,
                                              const float* __restrict__ cw,
                                              const float* __restrict__ cb,
                                              float* __restrict__ xc) {
    int idx = blockIdx.x * 256 + threadIdx.x; // B*L*128
    int c = idx & 127;
    int t = idx >> 7;
    int b = t >> 11;
    int l = t & 2047;
    float4 w = ((const float4*)cw)[c];
    float wk[4] = {w.x, w.y, w.z, w.w};
    float acc = cb[c];
#pragma unroll
    for (int k = 0; k < 4; k++) {
        int ll = l - 3 + k;
        if (ll >= 0) acc += xin[((size_t)(b * Lseq + ll)) * 128 + c] * wk[k];
    }
    xc[idx] = silu_f(acc);
}

// K3: xdb = xc @ x_proj_w^T (132 cols) + dt = softplus(dtr @ dt_proj_w^T + b)
__global__ __launch_bounds__(128) void k_xproj(const float* __restrict__ xc,
                                               const float* __restrict__ xpw,
                                               const float* __restrict__ dtw,
                                               const float* __restrict__ dtb,
                                               float* __restrict__ dt,
                                               float* __restrict__ Bm,
                                               float* __restrict__ Cm) {
    __shared__ float dtrs[16][4];
    int tid = threadIdx.x;
    int row0 = blockIdx.x * 16;
    float wreg[128];
    {
        const float4* wg = (const float4*)(xpw + (size_t)tid * 128);
#pragma unroll
        for (int i = 0; i < 32; i++) {
            float4 v = wg[i];
            wreg[i*4+0]=v.x; wreg[i*4+1]=v.y; wreg[i*4+2]=v.z; wreg[i*4+3]=v.w;
        }
    }
    int c2 = 128 + (tid >> 5);        // extra cols 128..131
    int j0 = (tid & 31) * 4;
    float4 we = *(const float4*)(xpw + (size_t)c2 * 128 + j0);
    for (int r = 0; r < 16; r++) {
        const float* xr = xc + (size_t)(row0 + r) * 128;   // uniform
        float a0=0.f,a1=0.f,a2=0.f,a3=0.f;
#pragma unroll
        for (int i = 0; i < 128; i += 4) {
            a0 = fmaf(xr[i+0], wreg[i+0], a0);
            a1 = fmaf(xr[i+1], wreg[i+1], a1);
            a2 = fmaf(xr[i+2], wreg[i+2], a2);
            a3 = fmaf(xr[i+3], wreg[i+3], a3);
        }
        float acc = (a0+a1)+(a2+a3);
        int row = row0 + r;
        if (tid < 4) dtrs[r][tid] = acc;
        else if (tid < 68) Bm[(size_t)row*64 + (tid-4)] = acc;
        else Cm[(size_t)row*64 + (tid-68)] = acc;
        float4 xr4 = ((const float4*)xr)[tid & 31];
        float p = xr4.x*we.x + xr4.y*we.y + xr4.z*we.z + xr4.w*we.w;
        p += __shfl_xor(p, 1); p += __shfl_xor(p, 2); p += __shfl_xor(p, 4);
        p += __shfl_xor(p, 8); p += __shfl_xor(p, 16);
        if ((tid & 31) == 0) Cm[(size_t)row*64 + 60 + (tid>>5)] = p;
    }
    __syncthreads();
    float4 w4 = ((const float4*)dtw)[tid];
    float bb = dtb[tid];
    for (int r = 0; r < 16; r++) {
        float xv = bb + dtrs[r][0]*w4.x + dtrs[r][1]*w4.y + dtrs[r][2]*w4.z + dtrs[r][3]*w4.w;
        dt[(size_t)(row0+r)*128 + tid] = softplus_f(xv);
    }
}

// K4: scan pass A
__global__ __launch_bounds__(256) void k_scanA(const float* __restrict__ dt,
                                               const float* __restrict__ xc,
                                               const float* __restrict__ Bm,
                                               const float* __restrict__ Alog,
                                               float* __restrict__ P,
                                               float* __restrict__ hloc) {
    int tid = threadIdx.x;
    int lane = tid & 63, wv = tid >> 6;
    int blk = blockIdx.x;           // ((b*32 + nc)*4 + dgq)
    int dgq = blk & 3;
    int t = blk >> 2;
    int nc = t & 31;
    int b = t >> 5;
    int dgroup = dgq * 4 + wv;
    int dd = lane >> 3, sg = lane & 7;
    int d = dgroup * 8 + dd;
    float A[8], h[8], Pp[8];
#pragma unroll
    for (int j = 0; j < 8; j++) {
        A[j] = -__expf(Alog[d*64 + sg*8 + j]);
        h[j] = 0.f; Pp[j] = 1.f;
    }
    int base = b * Lseq + nc * CT;
    for (int i = 0; i < CT; i++) {
        size_t off = (size_t)(base + i);
        float dtv = dt[off*128 + d];
        float xcv = xc[off*128 + d];
        const float4* bm4 = (const float4*)(Bm + off*64 + sg*8);
        float4 b0 = bm4[0], b1 = bm4[1];
        float bmv[8] = {b0.x,b0.y,b0.z,b0.w,b1.x,b1.y,b1.z,b1.w};
        float dtxc = dtv * xcv;
#pragma unroll
        for (int j = 0; j < 8; j++) {
            float a = __expf(dtv * A[j]);
            h[j] = fmaf(a, h[j], dtxc * bmv[j]);
            Pp[j] *= a;
        }
    }
    size_t idx0 = (((size_t)nc*4 + b)*128 + d)*64 + sg*8;
    float4* p4 = (float4*)(P + idx0);
    p4[0] = make_float4(Pp[0],Pp[1],Pp[2],Pp[3]);
    p4[1] = make_float4(Pp[4],Pp[5],Pp[6],Pp[7]);
    float4* h4 = (float4*)(hloc + idx0);
    h4[0] = make_float4(h[0],h[1],h[2],h[3]);
    h4[1] = make_float4(h[4],h[5],h[6],h[7]);
}

// K5: sequential combine over chunks; writes Hinit in-place into P
__global__ __launch_bounds__(256) void k_comb(float* __restrict__ P,
                                              const float* __restrict__ hloc) {
    int n = blockIdx.x * 256 + threadIdx.x;
    float pv[NC], hv[NC];
#pragma unroll
    for (int j = 0; j < NC; j++) {
        size_t idx = (size_t)j * 32768 + n;
        pv[j] = P[idx];
        hv[j] = hloc[idx];
    }
    float H = 0.f;
#pragma unroll
    for (int j = 0; j < NC; j++) {
        P[(size_t)j * 32768 + n] = H;
        H = fmaf(pv[j], H, hv[j]);
    }
}

// K6: scan pass B
__global__ __launch_bounds__(256) void k_scanB(const float* __restrict__ dt,
                                               const float* __restrict__ xc,
                                               const float* __restrict__ Bm,
                                               const float* __restrict__ Cm,
                                               const float* __restrict__ Alog,
                                               const float* __restrict__ Hinit,
                                               float* __restrict__ y) {
    int tid = threadIdx.x;
    int lane = tid & 63, wv = tid >> 6;
    int blk = blockIdx.x;
    int dgq = blk & 3;
    int t = blk >> 2;
    int nc = t & 31;
    int b = t >> 5;
    int dgroup = dgq * 4 + wv;
    int dd = lane >> 3, sg = lane & 7;
    int d = dgroup * 8 + dd;
    float A[8], h[8];
    size_t idx0 = (((size_t)nc*4 + b)*128 + d)*64 + sg*8;
    {
        const float4* h4 = (const float4*)(Hinit + idx0);
        float4 h0 = h4[0], h1 = h4[1];
        h[0]=h0.x; h[1]=h0.y; h[2]=h0.z; h[3]=h0.w;
        h[4]=h1.x; h[5]=h1.y; h[6]=h1.z; h[7]=h1.w;
    }
#pragma unroll
    for (int j = 0; j < 8; j++) A[j] = -__expf(Alog[d*64 + sg*8 + j]);
    int base = b * Lseq + nc * CT;
    for (int i = 0; i < CT; i++) {
        size_t off = (size_t)(base + i);
        float dtv = dt[off*128 + d];
        float xcv = xc[off*128 + d];
        const float4* bm4 = (const float4*)(Bm + off*64 + sg*8);
        float4 b0 = bm4[0], b1 = bm4[1];
        const float4* cm4 = (const float4*)(Cm + off*64 + sg*8);
        float4 c0 = cm4[0], c1 = cm4[1];
        float bmv[8] = {b0.x,b0.y,b0.z,b0.w,b1.x,b1.y,b1.z,b1.w};
        float cmv[8] = {c0.x,c0.y,c0.z,c0.w,c1.x,c1.y,c1.z,c1.w};
        float dtxc = dtv * xcv;
        float p = 0.f;
#pragma unroll
        for (int j = 0; j < 8; j++) {
            float a = __expf(dtv * A[j]);
            h[j] = fmaf(a, h[j], dtxc * bmv[j]);
            p = fmaf(h[j], cmv[j], p);
        }
        p += __shfl_xor(p, 1);
        p += __shfl_xor(p, 2);
        p += __shfl_xor(p, 4);
        if (sg == 0) y[off*128 + d] = p;
    }
}

// K7: gate + out_proj + leaky_relu + rms-groupnorm -> h2
__global__ __launch_bounds__(256) void k_gate(const float* __restrict__ y,
                                              const float* __restrict__ xc,
                                              const float* __restrict__ z,
                                              const float* __restrict__ Dp,
                                              const float* __restrict__ opw,
                                              const float* __restrict__ gamma,
                                              float* __restrict__ h2) {
    __shared__ __align__(16) float ys[16 * 128];
    __shared__ float hs[16 * 64];
    int tid = threadIdx.x;
    int row0 = blockIdx.x * 16;
#pragma unroll
    for (int i = 0; i < 8; i++) {
        int idx = tid + 256 * i;
        int r = idx >> 7, dd = idx & 127;
        size_t off = (size_t)(row0 + r);
        float yv = y[off * 128 + dd];
        float xcv = xc[off * 128 + dd];
        float zv = z[off * 128 + dd];
        ys[idx] = (yv + xcv * Dp[dd]) * silu_f(zv);
    }
    __syncthreads();
    int e = tid & 63, rr = tid >> 6;
    const float4* wr = (const float4*)(opw + (size_t)e * 128);
    float4 w[32];
#pragma unroll
    for (int i = 0; i < 32; i++) w[i] = wr[i];
#pragma unroll
    for (int j = 0; j < 4; j++) {
        int r = rr + 4 * j;
        const float4* a4 = (const float4*)(ys + r * 128);
        float acc = 0.f;
#pragma unroll
        for (int i = 0; i < 32; i++) {
            float4 a = a4[i], b = w[i];
            acc += a.x * b.x + a.y * b.y + a.z * b.z + a.w * b.w;
        }
        acc = acc >= 0.f ? acc : 0.01f * acc;
        hs[r * 64 + e] = acc;
    }
    __syncthreads();
#pragma unroll
    for (int j = 0; j < 4; j++) {
        int r = rr + 4 * j;
        int g = e >> 4;
        float ss = 0.f;
#pragma unroll
        for (int i = 0; i < 16; i++) {
            float v = hs[r * 64 + g * 16 + i];
            ss += v * v;
        }
        float rms = sqrtf(ss) * 0.25f;
        h2[(size_t)(row0 + r) * 64 + e] = hs[r * 64 + e] / (rms + 1e-5f) * gamma[e];
    }
}

// K-prep: weights to bf16. Wbf[c][k] = bf16(fcw[c][k]) (k = d*4+kk, natural).
// dwt[j][e][c] = bf16(fdw[c][e][3-j]).
__global__ __launch_bounds__(256) void k_prep(const float* __restrict__ fcw,
                                              const float* __restrict__ fdw,
                                              unsigned short* __restrict__ Wbf,
                                              unsigned short* __restrict__ dwt) {
    int i = blockIdx.x * 256 + threadIdx.x;   // grid 768 -> 196608
    if (i < 131072) {
        Wbf[i] = f2bf(fcw[i]);
    } else {
        int t = i - 131072;
        int j = t >> 14, e = (t >> 8) & 63, c = t & 255;
        dwt[t] = f2bf(fdw[(c * 64 + e) * 4 + (3 - j)]);
    }
}

// K8: FF conv1 + GLU via MFMA bf16. GEMM: M=t (im2col window), N=c(512), K=256.
__global__ __launch_bounds__(256) void k_ff1(const float* __restrict__ h2,
                                             const unsigned short* __restrict__ Wbf,
                                             const float* __restrict__ fcb,
                                             unsigned short* __restrict__ hh) {
    __shared__ unsigned short Alds[32 * 264];   // row pad 264 (+8) -> 2-way free
    int tid = threadIdx.x;
    int blk = blockIdx.x;           // b*65 + tt
    int tt = blk % 65, b = blk / 65;
    int t0 = tt * 32;
    // stage im2col A: A[t][d*4+kk] = bf16(h2[b][t-3+kk][d]), OOB -> 0
#pragma unroll
    for (int i = 0; i < 8; i++) {
        int idx = tid + 256 * i;    // 0..2047
        int tl = idx >> 6, d = idx & 63;
        int t = t0 + tl;
        unsigned short v[4];
#pragma unroll
        for (int kk = 0; kk < 4; kk++) {
            int ts = t - 3 + kk;
            float xv = (ts >= 0 && ts < Lseq) ? h2[((size_t)(b * Lseq + ts)) * 64 + d] : 0.f;
            v[kk] = f2bf(xv);
        }
        unsigned lo = (unsigned)v[0] | ((unsigned)v[1] << 16);
        unsigned hi = (unsigned)v[2] | ((unsigned)v[3] << 16);
        *(uint2*)(&Alds[tl * 264 + d * 4]) = make_uint2(lo, hi);
    }
    __syncthreads();
    int lane = tid & 63, w = tid >> 6;
    int l15 = lane & 15, quad = lane >> 4;
    f32x4 zero = {0.f, 0.f, 0.f, 0.f};
    f32x4 au[2][4], ag[2][4];
#pragma unroll
    for (int m = 0; m < 2; m++)
#pragma unroll
        for (int ci = 0; ci < 4; ci++) { au[m][ci] = zero; ag[m][ci] = zero; }
    for (int kc = 0; kc < 8; kc++) {
        bf16x8 a0 = *(const bf16x8*)(&Alds[l15 * 264 + kc * 32 + quad * 8]);
        bf16x8 a1 = *(const bf16x8*)(&Alds[(l15 + 16) * 264 + kc * 32 + quad * 8]);
#pragma unroll
        for (int ci = 0; ci < 4; ci++) {
            int cu = w * 64 + ci * 16 + l15;
            bf16x8 bu = *(const bf16x8*)(&Wbf[(size_t)cu * 256 + kc * 32 + quad * 8]);
            bf16x8 bg = *(const bf16x8*)(&Wbf[(size_t)(cu + 256) * 256 + kc * 32 + quad * 8]);
            au[0][ci] = __builtin_amdgcn_mfma_f32_16x16x32_bf16(a0, bu, au[0][ci], 0, 0, 0);
            au[1][ci] = __builtin_amdgcn_mfma_f32_16x16x32_bf16(a1, bu, au[1][ci], 0, 0, 0);
            ag[0][ci] = __builtin_amdgcn_mfma_f32_16x16x32_bf16(a0, bg, ag[0][ci], 0, 0, 0);
            ag[1][ci] = __builtin_amdgcn_mfma_f32_16x16x32_bf16(a1, bg, ag[1][ci], 0, 0, 0);
        }
    }
    float bub[4], bgb[4];
#pragma unroll
    for (int ci = 0; ci < 4; ci++) {
        int cu = w * 64 + ci * 16 + l15;
        bub[ci] = fcb[cu];
        bgb[ci] = fcb[cu + 256];
    }
#pragma unroll
    for (int m = 0; m < 2; m++)
#pragma unroll
        for (int ci = 0; ci < 4; ci++) {
            int cu = w * 64 + ci * 16 + l15;
#pragma unroll
            for (int r = 0; r < 4; r++) {
                int t = t0 + m * 16 + quad * 4 + r;
                if (t < LP3) {
                    float u = au[m][ci][r] + bub[ci];
                    float g = ag[m][ci][r] + bgb[ci];
                    hh[((size_t)(b * LP3 + t)) * 256 + cu] = f2bf(u * silu_f(g));
                }
            }
        }
}

// K9: FF deconv + residual via MFMA bf16. M=t(32/block), N=e(64), K=c(256)x4 taps.
__global__ __launch_bounds__(256) void k_ff2(const unsigned short* __restrict__ hh,
                                             const float* __restrict__ h2,
                                             const unsigned short* __restrict__ dwt,
                                             const float* __restrict__ db,
                                             float* __restrict__ out) {
    __shared__ float red[4][64][34];   // pad 34 -> 2-way free
    int tid = threadIdx.x;
    int blk = blockIdx.x;     // b*64 + lt
    int lt = blk & 63, b = blk >> 6;
    int t0 = lt * 32;
    int lane = tid & 63, w = tid >> 6;
    int l15 = lane & 15, quad = lane >> 4;
    f32x4 zero = {0.f, 0.f, 0.f, 0.f};
    f32x4 acc[2][4];
#pragma unroll
    for (int m = 0; m < 2; m++)
#pragma unroll
        for (int n = 0; n < 4; n++) acc[m][n] = zero;
#pragma unroll
    for (int kci = 0; kci < 2; kci++) {
        int kc = w * 2 + kci;
#pragma unroll
        for (int j = 0; j < 4; j++) {
            bf16x8 a0 = *(const bf16x8*)(&hh[((size_t)(b * LP3 + t0 + l15 + j)) * 256 + kc * 32 + quad * 8]);
            bf16x8 a1 = *(const bf16x8*)(&hh[((size_t)(b * LP3 + t0 + 16 + l15 + j)) * 256 + kc * 32 + quad * 8]);
#pragma unroll
            for (int n = 0; n < 4; n++) {
                bf16x8 bb = *(const bf16x8*)(&dwt[((size_t)(j * 64 + n * 16 + l15)) * 256 + kc * 32 + quad * 8]);
                acc[0][n] = __builtin_amdgcn_mfma_f32_16x16x32_bf16(a0, bb, acc[0][n], 0, 0, 0);
                acc[1][n] = __builtin_amdgcn_mfma_f32_16x16x32_bf16(a1, bb, acc[1][n], 0, 0, 0);
            }
        }
    }
#pragma unroll
    for (int m = 0; m < 2; m++)
#pragma unroll
        for (int n = 0; n < 4; n++) {
            *(float2*)(&red[w][lane][(m * 4 + n) * 4 + 0]) = make_float2(acc[m][n][0], acc[m][n][1]);
            *(float2*)(&red[w][lane][(m * 4 + n) * 4 + 2]) = make_float2(acc[m][n][2], acc[m][n][3]);
        }
    __syncthreads();
#pragma unroll
    for (int i = 0; i < 8; i++) {
        int o = tid + i * 256;     // 0..2047 = t-local*64 + e
        int tl = o >> 6, e = o & 63;
        int m = tl >> 4, qr = tl & 15;
        int q = qr >> 2, r = qr & 3;
        int n = e >> 4, el = e & 15;
        int srclane = q * 16 + el;
        int fi = (m * 4 + n) * 4 + r;
        float s = red[0][srclane][fi] + red[1][srclane][fi]
                + red[2][srclane][fi] + red[3][srclane][fi];
        size_t off = ((size_t)(b * Lseq + t0 + tl)) * 64 + e;
        out[off] = h2[off] + 0.5f * (s + db[e]);
    }
}

extern "C" void kernel_launch(void* const* d_in, const int* in_sizes, int n_in,
                              void* d_out, int out_size, void* d_ws, size_t ws_size,
                              hipStream_t stream) {
    const float* x      = (const float*)d_in[0];
    const float* ipw    = (const float*)d_in[1];
    const float* cw     = (const float*)d_in[2];
    const float* cb     = (const float*)d_in[3];
    const float* xpw    = (const float*)d_in[4];
    const float* dtw    = (const float*)d_in[5];
    const float* dtb    = (const float*)d_in[6];
    const float* Alog   = (const float*)d_in[7];
    const float* Dp     = (const float*)d_in[8];
    const float* opw    = (const float*)d_in[9];
    const float* gamma  = (const float*)d_in[10];
    const float* fcw    = (const float*)d_in[11];
    const float* fcb    = (const float*)d_in[12];
    const float* fdw    = (const float*)d_in[13];
    const float* fdb    = (const float*)d_in[14];
    float* out = (float*)d_out;
    float* ws = (float*)d_ws;

    float* z     = ws + OFF_Z;
    float* xc    = ws + OFF_XC;
    float* dt    = ws + OFF_DT;
    float* Bm    = ws + OFF_BM;
    float* Cm    = ws + OFF_CM;
    float* y     = ws + OFF_Y;
    float* h2    = ws + OFF_H2;
    float* xin   = ws + OFF_XIN;   // becomes hloc after k_conv
    float* P     = ws + OFF_P;     // becomes Hinit after k_comb; then bf16 weights
    unsigned short* Wbf = (unsigned short*)(ws + OFF_P);
    unsigned short* dwt = (unsigned short*)(ws + OFF_P + 65536);
    unsigned short* hh  = (unsigned short*)(ws + OFF_HH);

    hipLaunchKernelGGL(k_inproj, dim3(512), dim3(256), 0, stream, x, ipw, xin, z);
    hipLaunchKernelGGL(k_conv,   dim3(4096), dim3(256), 0, stream, xin, cw, cb, xc);
    hipLaunchKernelGGL(k_xproj,  dim3(512), dim3(128), 0, stream, xc, xpw, dtw, dtb, dt, Bm, Cm);
    hipLaunchKernelGGL(k_scanA,  dim3(512), dim3(256), 0, stream, dt, xc, Bm, Alog, P, xin);
    hipLaunchKernelGGL(k_comb,   dim3(128), dim3(256), 0, stream, P, xin);
    hipLaunchKernelGGL(k_scanB,  dim3(512), dim3(256), 0, stream, dt, xc, Bm, Cm, Alog, P, y);
    hipLaunchKernelGGL(k_prep,   dim3(768), dim3(256), 0, stream, fcw, fdw, Wbf, dwt);
    hipLaunchKernelGGL(k_gate,   dim3(512), dim3(256), 0, stream, y, xc, z, Dp, opw, gamma, h2);
    hipLaunchKernelGGL(k_ff1,    dim3(260), dim3(256), 0, stream, h2, Wbf, fcb, hh);
    hipLaunchKernelGGL(k_ff2,    dim3(256), dim3(256), 0, stream, hh, h2, dwt, fdb, out);
}

// Round 6
// 224.875 us; speedup vs baseline: 1.6845x; 1.1319x over previous
//
#include <hip/hip_runtime.h>
#include <math.h>

// Problem constants
#define Bsz 4
#define Lseq 2048
#define DIN 128
#define DST 64
#define FFIN 256
#define NC 32      // scan chunks
#define CT 64      // chunk length (NC*CT == Lseq)
#define LP3 2051   // Lseq + 3 (ff intermediate length)

// ws layout (float offsets) — total 8,019,968 floats < 8,388,608 (32 MiB proven)
#define OFF_Z     0u          // B*L*128 = 1,048,576
#define OFF_XC    1048576u
#define OFF_DT    2097152u
#define OFF_BM    3145728u    // B*L*64
#define OFF_CM    3670016u
#define OFF_Y     4194304u    // B*L*128
#define OFF_H2    5242880u    // B*L*64
#define OFF_XIN   5767168u    // dead after k_conv -> reused as hloc
#define OFF_P     6815744u    // scan P; becomes Hinit after k_comb
#define OFF_W     7864320u    // bf16 weights (311,296 elems = 155,648 float slots)
#define OFF_HH    OFF_DT      // hh bf16 overlays dt (+1536 slots into Bm) — both dead

// bf16 weight sub-offsets (elements). hi parts first, then lo parts for the
// split-precision GEMM weights (ipw/wx/opw).
#define W_IPW   0u        // [256][64]
#define W_WX    16384u    // [256][128]: rows 0..127 folded-dt, 128..191 B, 192..255 C
#define W_OPW   49152u    // [64][128]
#define W_FF1   57344u    // [512][256]
#define W_DWT   188416u   // [4][64][256]
#define W_LO    253952u   // lo parts, 1:1 with hi indices [0, 57344)
#define W_TOTAL 311296u

typedef __attribute__((ext_vector_type(8))) short bf16x8;
typedef __attribute__((ext_vector_type(4))) float f32x4;

__device__ __forceinline__ float silu_f(float x) {
    return x / (1.f + __expf(-x));
}
__device__ __forceinline__ float softplus_f(float x) {
    return x > 0.f ? x + log1pf(__expf(-x)) : log1pf(__expf(x));
}
__device__ __forceinline__ unsigned short f2bf(float f) {
    union { float f; unsigned u; } v; v.f = f;
    unsigned r = v.u + 0x7FFFu + ((v.u >> 16) & 1u);
    return (unsigned short)(r >> 16);
}
__device__ __forceinline__ float bf2f(unsigned short u) {
    union { unsigned u; float f; } v; v.u = ((unsigned)u) << 16;
    return v.f;
}
// split f32 -> (hi, lo) bf16 pair
__device__ __forceinline__ void splitbf(float x, unsigned short* hi, unsigned short* lo) {
    unsigned short h = f2bf(x);
    *hi = h;
    *lo = f2bf(x - bf2f(h));
}

// K0: all weights -> bf16 hi(+lo for GEMM weights), plus dt-fold into Wx.
__global__ __launch_bounds__(256) void k_prep(const float* __restrict__ ipw,
                                              const float* __restrict__ xpw,
                                              const float* __restrict__ dtw,
                                              const float* __restrict__ opw,
                                              const float* __restrict__ fcw,
                                              const float* __restrict__ fdw,
                                              unsigned short* __restrict__ Wb) {
    unsigned i = blockIdx.x * 256 + threadIdx.x;
    if (i >= W_LO) return;
    float val;
    if (i < W_WX) {
        val = ipw[i];
    } else if (i < W_OPW) {
        unsigned t = i - W_WX;
        int n = t >> 7, k = t & 127;
        if (n < 128) {
            val = dtw[n*4+0]*xpw[0*128+k] + dtw[n*4+1]*xpw[1*128+k]
                + dtw[n*4+2]*xpw[2*128+k] + dtw[n*4+3]*xpw[3*128+k];
        } else if (n < 192) {
            val = xpw[(n - 128 + 4)*128 + k];
        } else {
            val = xpw[(n - 192 + 68)*128 + k];
        }
    } else if (i < W_FF1) {
        val = opw[i - W_OPW];
    } else if (i < W_DWT) {
        val = fcw[i - W_FF1];
    } else {
        unsigned t = i - W_DWT;
        int j = t >> 14, e = (t >> 8) & 63, c = t & 255;
        val = fdw[(c*64 + e)*4 + (3 - j)];
    }
    if (i < W_FF1) {
        unsigned short h, l;
        splitbf(val, &h, &l);
        Wb[i] = h;
        Wb[W_LO + i] = l;
    } else {
        Wb[i] = f2bf(val);
    }
}

// K1: in_proj via split-bf16 MFMA. GEMM M=8192(32/block), N=256, K=64.
__global__ __launch_bounds__(256) void k_inproj(const float* __restrict__ x,
                                                const unsigned short* __restrict__ Wb,
                                                float* __restrict__ xin,
                                                float* __restrict__ z) {
    __shared__ unsigned short Ahi[32 * 72];
    __shared__ unsigned short Alo[32 * 72];
    int tid = threadIdx.x;
    int row0 = blockIdx.x * 32;
    const unsigned short* bh = Wb + W_IPW;
    const unsigned short* bl = Wb + W_LO + W_IPW;
#pragma unroll
    for (int i = 0; i < 2; i++) {
        int j = tid + 256 * i;             // float4 index over [32][64]
        int r = j >> 4, c0 = (j & 15) * 4;
        float4 v = *(const float4*)(x + (size_t)(row0 + r) * 64 + c0);
        unsigned short* ph = &Ahi[r * 72 + c0];
        unsigned short* pl = &Alo[r * 72 + c0];
        splitbf(v.x, ph+0, pl+0); splitbf(v.y, ph+1, pl+1);
        splitbf(v.z, ph+2, pl+2); splitbf(v.w, ph+3, pl+3);
    }
    __syncthreads();
    int lane = tid & 63, w = tid >> 6;
    int l15 = lane & 15, quad = lane >> 4;
    int n0 = w * 64;
    f32x4 zero = {0.f,0.f,0.f,0.f};
    f32x4 acc[2][4];
#pragma unroll
    for (int mi = 0; mi < 2; mi++)
#pragma unroll
        for (int ni = 0; ni < 4; ni++) acc[mi][ni] = zero;
#pragma unroll
    for (int kt = 0; kt < 2; kt++) {
        bf16x8 Bh[4], Bl[4];
#pragma unroll
        for (int ni = 0; ni < 4; ni++) {
            size_t boff = (size_t)(n0 + ni*16 + l15) * 64 + kt*32 + quad*8;
            Bh[ni] = *(const bf16x8*)(&bh[boff]);
            Bl[ni] = *(const bf16x8*)(&bl[boff]);
        }
#pragma unroll
        for (int mi = 0; mi < 2; mi++) {
            bf16x8 ah = *(const bf16x8*)(&Ahi[(mi*16 + l15) * 72 + kt*32 + quad*8]);
            bf16x8 al = *(const bf16x8*)(&Alo[(mi*16 + l15) * 72 + kt*32 + quad*8]);
#pragma unroll
            for (int ni = 0; ni < 4; ni++) {
                acc[mi][ni] = __builtin_amdgcn_mfma_f32_16x16x32_bf16(ah, Bh[ni], acc[mi][ni], 0, 0, 0);
                acc[mi][ni] = __builtin_amdgcn_mfma_f32_16x16x32_bf16(al, Bh[ni], acc[mi][ni], 0, 0, 0);
                acc[mi][ni] = __builtin_amdgcn_mfma_f32_16x16x32_bf16(ah, Bl[ni], acc[mi][ni], 0, 0, 0);
            }
        }
    }
#pragma unroll
    for (int mi = 0; mi < 2; mi++)
#pragma unroll
        for (int ni = 0; ni < 4; ni++) {
            int col = n0 + ni*16 + l15;
#pragma unroll
            for (int r = 0; r < 4; r++) {
                int row = row0 + mi*16 + quad*4 + r;
                if (col < 128) xin[(size_t)row * 128 + col] = acc[mi][ni][r];
                else           z[(size_t)row * 128 + (col - 128)] = acc[mi][ni][r];
            }
        }
}

// K2: causal depthwise conv + silu -> xc
__global__ __launch_bounds__(256) void k_conv(const float* __restrict__ xin,
                                              const float* __restrict__ cw,
                                              const float* __restrict__ cb,
                                              float* __restrict__ xc) {
    int idx = blockIdx.x * 256 + threadIdx.x;
    int c = idx & 127;
    int t = idx >> 7;
    int b = t >> 11;
    int l = t & 2047;
    float4 w = ((const float4*)cw)[c];
    float wk[4] = {w.x, w.y, w.z, w.w};
    float acc = cb[c];
#pragma unroll
    for (int k = 0; k < 4; k++) {
        int ll = l - 3 + k;
        if (ll >= 0) acc += xin[((size_t)(b * Lseq + ll)) * 128 + c] * wk[k];
    }
    xc[idx] = silu_f(acc);
}

// K3: x_proj + folded dt_proj via split-bf16 MFMA. M=8192(32/block), N=256, K=128.
__global__ __launch_bounds__(256) void k_xproj(const float* __restrict__ xc,
                                               const unsigned short* __restrict__ Wb,
                                               const float* __restrict__ dtb,
                                               float* __restrict__ dt,
                                               float* __restrict__ Bm,
                                               float* __restrict__ Cm) {
    __shared__ unsigned short Ahi[32 * 136];
    __shared__ unsigned short Alo[32 * 136];
    int tid = threadIdx.x;
    int row0 = blockIdx.x * 32;
    const unsigned short* bh = Wb + W_WX;
    const unsigned short* bl = Wb + W_LO + W_WX;
#pragma unroll
    for (int i = 0; i < 4; i++) {
        int j = tid + 256 * i;             // float4 index over [32][128]
        int r = j >> 5, c0 = (j & 31) * 4;
        float4 v = *(const float4*)(xc + (size_t)(row0 + r) * 128 + c0);
        unsigned short* ph = &Ahi[r * 136 + c0];
        unsigned short* pl = &Alo[r * 136 + c0];
        splitbf(v.x, ph+0, pl+0); splitbf(v.y, ph+1, pl+1);
        splitbf(v.z, ph+2, pl+2); splitbf(v.w, ph+3, pl+3);
    }
    __syncthreads();
    int lane = tid & 63, w = tid >> 6;
    int l15 = lane & 15, quad = lane >> 4;
    int n0 = w * 64;
    f32x4 zero = {0.f,0.f,0.f,0.f};
    f32x4 acc[2][4];
#pragma unroll
    for (int mi = 0; mi < 2; mi++)
#pragma unroll
        for (int ni = 0; ni < 4; ni++) acc[mi][ni] = zero;
#pragma unroll
    for (int kt = 0; kt < 4; kt++) {
        bf16x8 Bh[4], Bl[4];
#pragma unroll
        for (int ni = 0; ni < 4; ni++) {
            size_t boff = (size_t)(n0 + ni*16 + l15) * 128 + kt*32 + quad*8;
            Bh[ni] = *(const bf16x8*)(&bh[boff]);
            Bl[ni] = *(const bf16x8*)(&bl[boff]);
        }
#pragma unroll
        for (int mi = 0; mi < 2; mi++) {
            bf16x8 ah = *(const bf16x8*)(&Ahi[(mi*16 + l15) * 136 + kt*32 + quad*8]);
            bf16x8 al = *(const bf16x8*)(&Alo[(mi*16 + l15) * 136 + kt*32 + quad*8]);
#pragma unroll
            for (int ni = 0; ni < 4; ni++) {
                acc[mi][ni] = __builtin_amdgcn_mfma_f32_16x16x32_bf16(ah, Bh[ni], acc[mi][ni], 0, 0, 0);
                acc[mi][ni] = __builtin_amdgcn_mfma_f32_16x16x32_bf16(al, Bh[ni], acc[mi][ni], 0, 0, 0);
                acc[mi][ni] = __builtin_amdgcn_mfma_f32_16x16x32_bf16(ah, Bl[ni], acc[mi][ni], 0, 0, 0);
            }
        }
    }
#pragma unroll
    for (int mi = 0; mi < 2; mi++)
#pragma unroll
        for (int ni = 0; ni < 4; ni++) {
            int col = n0 + ni*16 + l15;
#pragma unroll
            for (int r = 0; r < 4; r++) {
                int row = row0 + mi*16 + quad*4 + r;
                float v = acc[mi][ni][r];
                if (col < 128)      dt[(size_t)row * 128 + col] = softplus_f(v + dtb[col]);
                else if (col < 192) Bm[(size_t)row * 64 + (col - 128)] = v;
                else                Cm[(size_t)row * 64 + (col - 192)] = v;
            }
        }
}

// K4: scan pass A
__global__ __launch_bounds__(256) void k_scanA(const float* __restrict__ dt,
                                               const float* __restrict__ xc,
                                               const float* __restrict__ Bm,
                                               const float* __restrict__ Alog,
                                               float* __restrict__ P,
                                               float* __restrict__ hloc) {
    int tid = threadIdx.x;
    int lane = tid & 63, wv = tid >> 6;
    int blk = blockIdx.x;           // ((b*32 + nc)*4 + dgq)
    int dgq = blk & 3;
    int t = blk >> 2;
    int nc = t & 31;
    int b = t >> 5;
    int dgroup = dgq * 4 + wv;
    int dd = lane >> 3, sg = lane & 7;
    int d = dgroup * 8 + dd;
    float A[8], h[8], Pp[8];
#pragma unroll
    for (int j = 0; j < 8; j++) {
        A[j] = -__expf(Alog[d*64 + sg*8 + j]);
        h[j] = 0.f; Pp[j] = 1.f;
    }
    int base = b * Lseq + nc * CT;
    for (int i = 0; i < CT; i++) {
        size_t off = (size_t)(base + i);
        float dtv = dt[off*128 + d];
        float xcv = xc[off*128 + d];
        const float4* bm4 = (const float4*)(Bm + off*64 + sg*8);
        float4 b0 = bm4[0], b1 = bm4[1];
        float bmv[8] = {b0.x,b0.y,b0.z,b0.w,b1.x,b1.y,b1.z,b1.w};
        float dtxc = dtv * xcv;
#pragma unroll
        for (int j = 0; j < 8; j++) {
            float a = __expf(dtv * A[j]);
            h[j] = fmaf(a, h[j], dtxc * bmv[j]);
            Pp[j] *= a;
        }
    }
    size_t idx0 = (((size_t)nc*4 + b)*128 + d)*64 + sg*8;
    float4* p4 = (float4*)(P + idx0);
    p4[0] = make_float4(Pp[0],Pp[1],Pp[2],Pp[3]);
    p4[1] = make_float4(Pp[4],Pp[5],Pp[6],Pp[7]);
    float4* h4 = (float4*)(hloc + idx0);
    h4[0] = make_float4(h[0],h[1],h[2],h[3]);
    h4[1] = make_float4(h[4],h[5],h[6],h[7]);
}

// K5: sequential combine over chunks; writes Hinit in-place into P
__global__ __launch_bounds__(256) void k_comb(float* __restrict__ P,
                                              const float* __restrict__ hloc) {
    int n = blockIdx.x * 256 + threadIdx.x;
    float pv[NC], hv[NC];
#pragma unroll
    for (int j = 0; j < NC; j++) {
        size_t idx = (size_t)j * 32768 + n;
        pv[j] = P[idx];
        hv[j] = hloc[idx];
    }
    float H = 0.f;
#pragma unroll
    for (int j = 0; j < NC; j++) {
        P[(size_t)j * 32768 + n] = H;
        H = fmaf(pv[j], H, hv[j]);
    }
}

// K6: scan pass B
__global__ __launch_bounds__(256) void k_scanB(const float* __restrict__ dt,
                                               const float* __restrict__ xc,
                                               const float* __restrict__ Bm,
                                               const float* __restrict__ Cm,
                                               const float* __restrict__ Alog,
                                               const float* __restrict__ Hinit,
                                               float* __restrict__ y) {
    int tid = threadIdx.x;
    int lane = tid & 63, wv = tid >> 6;
    int blk = blockIdx.x;
    int dgq = blk & 3;
    int t = blk >> 2;
    int nc = t & 31;
    int b = t >> 5;
    int dgroup = dgq * 4 + wv;
    int dd = lane >> 3, sg = lane & 7;
    int d = dgroup * 8 + dd;
    float A[8], h[8];
    size_t idx0 = (((size_t)nc*4 + b)*128 + d)*64 + sg*8;
    {
        const float4* h4 = (const float4*)(Hinit + idx0);
        float4 h0 = h4[0], h1 = h4[1];
        h[0]=h0.x; h[1]=h0.y; h[2]=h0.z; h[3]=h0.w;
        h[4]=h1.x; h[5]=h1.y; h[6]=h1.z; h[7]=h1.w;
    }
#pragma unroll
    for (int j = 0; j < 8; j++) A[j] = -__expf(Alog[d*64 + sg*8 + j]);
    int base = b * Lseq + nc * CT;
    for (int i = 0; i < CT; i++) {
        size_t off = (size_t)(base + i);
        float dtv = dt[off*128 + d];
        float xcv = xc[off*128 + d];
        const float4* bm4 = (const float4*)(Bm + off*64 + sg*8);
        float4 b0 = bm4[0], b1 = bm4[1];
        const float4* cm4 = (const float4*)(Cm + off*64 + sg*8);
        float4 c0 = cm4[0], c1 = cm4[1];
        float bmv[8] = {b0.x,b0.y,b0.z,b0.w,b1.x,b1.y,b1.z,b1.w};
        float cmv[8] = {c0.x,c0.y,c0.z,c0.w,c1.x,c1.y,c1.z,c1.w};
        float dtxc = dtv * xcv;
        float p = 0.f;
#pragma unroll
        for (int j = 0; j < 8; j++) {
            float a = __expf(dtv * A[j]);
            h[j] = fmaf(a, h[j], dtxc * bmv[j]);
            p = fmaf(h[j], cmv[j], p);
        }
        p += __shfl_xor(p, 1);
        p += __shfl_xor(p, 2);
        p += __shfl_xor(p, 4);
        if (sg == 0) y[off*128 + d] = p;
    }
}

// K7: gate + out_proj (split-bf16 MFMA) + leaky_relu + in-register groupnorm -> h2
// GEMM M=8192(32/block), N=64, K=128. n-tile == norm group (16 cols).
__global__ __launch_bounds__(256) void k_gate(const float* __restrict__ y,
                                              const float* __restrict__ xc,
                                              const float* __restrict__ z,
                                              const float* __restrict__ Dp,
                                              const unsigned short* __restrict__ Wb,
                                              const float* __restrict__ gamma,
                                              float* __restrict__ h2) {
    __shared__ unsigned short Ahi[32 * 136];
    __shared__ unsigned short Alo[32 * 136];
    int tid = threadIdx.x;
    int row0 = blockIdx.x * 32;
    const unsigned short* bhp = Wb + W_OPW;
    const unsigned short* blp = Wb + W_LO + W_OPW;
#pragma unroll
    for (int i = 0; i < 4; i++) {
        int j = tid + 256 * i;
        int r = j >> 5, c0 = (j & 31) * 4;
        size_t off = (size_t)(row0 + r) * 128 + c0;
        float4 yv = *(const float4*)(y + off);
        float4 xv = *(const float4*)(xc + off);
        float4 zv = *(const float4*)(z + off);
        float4 dv = *(const float4*)(Dp + c0);
        unsigned short* ph = &Ahi[r * 136 + c0];
        unsigned short* pl = &Alo[r * 136 + c0];
        splitbf((yv.x + xv.x * dv.x) * silu_f(zv.x), ph+0, pl+0);
        splitbf((yv.y + xv.y * dv.y) * silu_f(zv.y), ph+1, pl+1);
        splitbf((yv.z + xv.z * dv.z) * silu_f(zv.z), ph+2, pl+2);
        splitbf((yv.w + xv.w * dv.w) * silu_f(zv.w), ph+3, pl+3);
    }
    __syncthreads();
    int lane = tid & 63, w = tid >> 6;
    int l15 = lane & 15, quad = lane >> 4;
    int mi = w & 1, nh = w >> 1;   // wave: m-tile mi, n-tiles {2nh, 2nh+1}
    f32x4 zero = {0.f,0.f,0.f,0.f};
    f32x4 acc[2] = {zero, zero};
#pragma unroll
    for (int kt = 0; kt < 4; kt++) {
        bf16x8 ah = *(const bf16x8*)(&Ahi[(mi*16 + l15) * 136 + kt*32 + quad*8]);
        bf16x8 al = *(const bf16x8*)(&Alo[(mi*16 + l15) * 136 + kt*32 + quad*8]);
#pragma unroll
        for (int nl = 0; nl < 2; nl++) {
            size_t boff = (size_t)((nh*2 + nl)*16 + l15) * 128 + kt*32 + quad*8;
            bf16x8 Bh = *(const bf16x8*)(&bhp[boff]);
            bf16x8 Bl = *(const bf16x8*)(&blp[boff]);
            acc[nl] = __builtin_amdgcn_mfma_f32_16x16x32_bf16(ah, Bh, acc[nl], 0, 0, 0);
            acc[nl] = __builtin_amdgcn_mfma_f32_16x16x32_bf16(al, Bh, acc[nl], 0, 0, 0);
            acc[nl] = __builtin_amdgcn_mfma_f32_16x16x32_bf16(ah, Bl, acc[nl], 0, 0, 0);
        }
    }
#pragma unroll
    for (int nl = 0; nl < 2; nl++) {
        int g = nh*2 + nl;
        float gm = gamma[g*16 + l15];
#pragma unroll
        for (int r = 0; r < 4; r++) {
            float v = acc[nl][r];
            v = v >= 0.f ? v : 0.01f * v;
            float ss = v * v;
            ss += __shfl_xor(ss, 1);
            ss += __shfl_xor(ss, 2);
            ss += __shfl_xor(ss, 4);
            ss += __shfl_xor(ss, 8);
            float rms = sqrtf(ss) * 0.25f;
            int row = row0 + mi*16 + quad*4 + r;
            h2[(size_t)row * 64 + g*16 + l15] = v / (rms + 1e-5f) * gm;
        }
    }
}

// K8: FF conv1 + GLU via MFMA bf16. GEMM: M=t (im2col), N=c(512), K=256.
__global__ __launch_bounds__(256) void k_ff1(const float* __restrict__ h2,
                                             const unsigned short* __restrict__ Wb,
                                             const float* __restrict__ fcb,
                                             unsigned short* __restrict__ hh) {
    __shared__ unsigned short Alds[32 * 264];
    int tid = threadIdx.x;
    int blk = blockIdx.x;           // b*65 + tt
    int tt = blk % 65, b = blk / 65;
    int t0 = tt * 32;
    const unsigned short* Wbf = Wb + W_FF1;
#pragma unroll
    for (int i = 0; i < 8; i++) {
        int idx = tid + 256 * i;    // 0..2047
        int tl = idx >> 6, d = idx & 63;
        int t = t0 + tl;
        unsigned short v[4];
#pragma unroll
        for (int kk = 0; kk < 4; kk++) {
            int ts = t - 3 + kk;
            float xv = (ts >= 0 && ts < Lseq) ? h2[((size_t)(b * Lseq + ts)) * 64 + d] : 0.f;
            v[kk] = f2bf(xv);
        }
        unsigned lo = (unsigned)v[0] | ((unsigned)v[1] << 16);
        unsigned hi = (unsigned)v[2] | ((unsigned)v[3] << 16);
        *(uint2*)(&Alds[tl * 264 + d * 4]) = make_uint2(lo, hi);
    }
    __syncthreads();
    int lane = tid & 63, w = tid >> 6;
    int l15 = lane & 15, quad = lane >> 4;
    f32x4 zero = {0.f, 0.f, 0.f, 0.f};
    f32x4 au[2][4], ag[2][4];
#pragma unroll
    for (int m = 0; m < 2; m++)
#pragma unroll
        for (int ci = 0; ci < 4; ci++) { au[m][ci] = zero; ag[m][ci] = zero; }
    for (int kc = 0; kc < 8; kc++) {
        bf16x8 a0 = *(const bf16x8*)(&Alds[l15 * 264 + kc * 32 + quad * 8]);
        bf16x8 a1 = *(const bf16x8*)(&Alds[(l15 + 16) * 264 + kc * 32 + quad * 8]);
#pragma unroll
        for (int ci = 0; ci < 4; ci++) {
            int cu = w * 64 + ci * 16 + l15;
            bf16x8 bu = *(const bf16x8*)(&Wbf[(size_t)cu * 256 + kc * 32 + quad * 8]);
            bf16x8 bg = *(const bf16x8*)(&Wbf[(size_t)(cu + 256) * 256 + kc * 32 + quad * 8]);
            au[0][ci] = __builtin_amdgcn_mfma_f32_16x16x32_bf16(a0, bu, au[0][ci], 0, 0, 0);
            au[1][ci] = __builtin_amdgcn_mfma_f32_16x16x32_bf16(a1, bu, au[1][ci], 0, 0, 0);
            ag[0][ci] = __builtin_amdgcn_mfma_f32_16x16x32_bf16(a0, bg, ag[0][ci], 0, 0, 0);
            ag[1][ci] = __builtin_amdgcn_mfma_f32_16x16x32_bf16(a1, bg, ag[1][ci], 0, 0, 0);
        }
    }
    float bub[4], bgb[4];
#pragma unroll
    for (int ci = 0; ci < 4; ci++) {
        int cu = w * 64 + ci * 16 + l15;
        bub[ci] = fcb[cu];
        bgb[ci] = fcb[cu + 256];
    }
#pragma unroll
    for (int m = 0; m < 2; m++)
#pragma unroll
        for (int ci = 0; ci < 4; ci++) {
            int cu = w * 64 + ci * 16 + l15;
#pragma unroll
            for (int r = 0; r < 4; r++) {
                int t = t0 + m * 16 + quad * 4 + r;
                if (t < LP3) {
                    float u = au[m][ci][r] + bub[ci];
                    float g = ag[m][ci][r] + bgb[ci];
                    hh[((size_t)(b * LP3 + t)) * 256 + cu] = f2bf(u * silu_f(g));
                }
            }
        }
}

// K9: FF deconv + residual via MFMA bf16. M=t(32/block), N=e(64), K=c(256)x4 taps.
__global__ __launch_bounds__(256) void k_ff2(const unsigned short* __restrict__ hh,
                                             const float* __restrict__ h2,
                                             const unsigned short* __restrict__ Wb,
                                             const float* __restrict__ db,
                                             float* __restrict__ out) {
    __shared__ float red[4][64][34];
    int tid = threadIdx.x;
    int blk = blockIdx.x;     // b*64 + lt
    int lt = blk & 63, b = blk >> 6;
    int t0 = lt * 32;
    const unsigned short* dwt = Wb + W_DWT;
    int lane = tid & 63, w = tid >> 6;
    int l15 = lane & 15, quad = lane >> 4;
    f32x4 zero = {0.f, 0.f, 0.f, 0.f};
    f32x4 acc[2][4];
#pragma unroll
    for (int m = 0; m < 2; m++)
#pragma unroll
        for (int n = 0; n < 4; n++) acc[m][n] = zero;
#pragma unroll
    for (int kci = 0; kci < 2; kci++) {
        int kc = w * 2 + kci;
#pragma unroll
        for (int j = 0; j < 4; j++) {
            bf16x8 a0 = *(const bf16x8*)(&hh[((size_t)(b * LP3 + t0 + l15 + j)) * 256 + kc * 32 + quad * 8]);
            bf16x8 a1 = *(const bf16x8*)(&hh[((size_t)(b * LP3 + t0 + 16 + l15 + j)) * 256 + kc * 32 + quad * 8]);
#pragma unroll
            for (int n = 0; n < 4; n++) {
                bf16x8 bb = *(const bf16x8*)(&dwt[((size_t)(j * 64 + n * 16 + l15)) * 256 + kc * 32 + quad * 8]);
                acc[0][n] = __builtin_amdgcn_mfma_f32_16x16x32_bf16(a0, bb, acc[0][n], 0, 0, 0);
                acc[1][n] = __builtin_amdgcn_mfma_f32_16x16x32_bf16(a1, bb, acc[1][n], 0, 0, 0);
            }
        }
    }
#pragma unroll
    for (int m = 0; m < 2; m++)
#pragma unroll
        for (int n = 0; n < 4; n++) {
            *(float2*)(&red[w][lane][(m * 4 + n) * 4 + 0]) = make_float2(acc[m][n][0], acc[m][n][1]);
            *(float2*)(&red[w][lane][(m * 4 + n) * 4 + 2]) = make_float2(acc[m][n][2], acc[m][n][3]);
        }
    __syncthreads();
#pragma unroll
    for (int i = 0; i < 8; i++) {
        int o = tid + i * 256;
        int tl = o >> 6, e = o & 63;
        int m = tl >> 4, qr = tl & 15;
        int q = qr >> 2, r = qr & 3;
        int n = e >> 4, el = e & 15;
        int srclane = q * 16 + el;
        int fi = (m * 4 + n) * 4 + r;
        float s = red[0][srclane][fi] + red[1][srclane][fi]
                + red[2][srclane][fi] + red[3][srclane][fi];
        size_t off = ((size_t)(b * Lseq + t0 + tl)) * 64 + e;
        out[off] = h2[off] + 0.5f * (s + db[e]);
    }
}

extern "C" void kernel_launch(void* const* d_in, const int* in_sizes, int n_in,
                              void* d_out, int out_size, void* d_ws, size_t ws_size,
                              hipStream_t stream) {
    const float* x      = (const float*)d_in[0];
    const float* ipw    = (const float*)d_in[1];
    const float* cw     = (const float*)d_in[2];
    const float* cb     = (const float*)d_in[3];
    const float* xpw    = (const float*)d_in[4];
    const float* dtw    = (const float*)d_in[5];
    const float* dtb    = (const float*)d_in[6];
    const float* Alog   = (const float*)d_in[7];
    const float* Dp     = (const float*)d_in[8];
    const float* opw    = (const float*)d_in[9];
    const float* gamma  = (const float*)d_in[10];
    const float* fcw    = (const float*)d_in[11];
    const float* fcb    = (const float*)d_in[12];
    const float* fdw    = (const float*)d_in[13];
    const float* fdb    = (const float*)d_in[14];
    float* out = (float*)d_out;
    float* ws = (float*)d_ws;

    float* z     = ws + OFF_Z;
    float* xc    = ws + OFF_XC;
    float* dt    = ws + OFF_DT;
    float* Bm    = ws + OFF_BM;
    float* Cm    = ws + OFF_CM;
    float* y     = ws + OFF_Y;
    float* h2    = ws + OFF_H2;
    float* xin   = ws + OFF_XIN;   // becomes hloc after k_conv
    float* P     = ws + OFF_P;     // becomes Hinit after k_comb
    unsigned short* Wb = (unsigned short*)(ws + OFF_W);
    unsigned short* hh = (unsigned short*)(ws + OFF_HH);

    hipLaunchKernelGGL(k_prep,   dim3(992), dim3(256), 0, stream, ipw, xpw, dtw, opw, fcw, fdw, Wb);
    hipLaunchKernelGGL(k_inproj, dim3(256), dim3(256), 0, stream, x, Wb, xin, z);
    hipLaunchKernelGGL(k_conv,   dim3(4096), dim3(256), 0, stream, xin, cw, cb, xc);
    hipLaunchKernelGGL(k_xproj,  dim3(256), dim3(256), 0, stream, xc, Wb, dtb, dt, Bm, Cm);
    hipLaunchKernelGGL(k_scanA,  dim3(512), dim3(256), 0, stream, dt, xc, Bm, Alog, P, xin);
    hipLaunchKernelGGL(k_comb,   dim3(128), dim3(256), 0, stream, P, xin);
    hipLaunchKernelGGL(k_scanB,  dim3(512), dim3(256), 0, stream, dt, xc, Bm, Cm, Alog, P, y);
    hipLaunchKernelGGL(k_gate,   dim3(256), dim3(256), 0, stream, y, xc, z, Dp, Wb, gamma, h2);
    hipLaunchKernelGGL(k_ff1,    dim3(260), dim3(256), 0, stream, h2, Wb, fcb, hh);
    hipLaunchKernelGGL(k_ff2,    dim3(256), dim3(256), 0, stream, hh, h2, Wb, fdb, out);
}